// Round 5
// baseline (761.538 us; speedup 1.0000x reference)
//
#include <hip/hip_runtime.h>
#include <hip/hip_bf16.h>
#include <cstdint>

typedef __attribute__((ext_vector_type(4))) float f32x4;
typedef __attribute__((ext_vector_type(8))) short s16x8;

#define CAP 128   // bucket capacity; deg ~ Poisson(32), P(any node > 128) ~ 1e-13

__device__ inline unsigned short f2bf(float f) {
    unsigned u = __float_as_uint(f);
    u = (u + 0x7fffu + ((u >> 16) & 1u)) >> 16;   // round-to-nearest-even
    return (unsigned short)u;
}
__device__ inline float bf_lo(unsigned x) { return __uint_as_float(x << 16); }
__device__ inline float bf_hi(unsigned x) { return __uint_as_float(x & 0xffff0000u); }

// ================= K1: convX | bucket-scatter | convW (independent, fused) ======
// CSR chain (hist -> scan1 -> scan2 -> scatter) replaced by one atomic-append
// into fixed-stride buckets: rank = atomicAdd(cnt[r]); buckets[r*CAP+rank] = c.
// Rank order was already atomic-nondeterministic in the old hist, so summation
// semantics are unchanged.
__global__ __launch_bounds__(256) void k1_prep(
    const float* __restrict__ X, unsigned short* __restrict__ Xb,
    const float* __restrict__ W, unsigned short* __restrict__ Wb,
    const int* __restrict__ rows, const int* __restrict__ colsIn,
    int* __restrict__ cnt, int* __restrict__ buckets,
    int nconvx, int nscat, int e) {
    const int tid = threadIdx.x;
    const int b = blockIdx.x;
    if (b < nconvx) {
        // X f32 -> bf16, 8 elems/thread (staged; R3 showed direct-f32 gemm is slower)
        size_t i = ((size_t)b * 256 + tid) * 8;
        f32x4 x0 = *(const f32x4*)(X + i);
        f32x4 x1 = *(const f32x4*)(X + i + 4);
        s16x8 r;
        r[0] = (short)f2bf(x0.x); r[1] = (short)f2bf(x0.y);
        r[2] = (short)f2bf(x0.z); r[3] = (short)f2bf(x0.w);
        r[4] = (short)f2bf(x1.x); r[5] = (short)f2bf(x1.y);
        r[6] = (short)f2bf(x1.z); r[7] = (short)f2bf(x1.w);
        *(s16x8*)(Xb + i) = r;
    } else if (b < nconvx + nscat) {
        int i = (b - nconvx) * 256 + tid;
        if (i < e) {
            int r = rows[i];
            int rk = atomicAdd(&cnt[r], 1);
            if (rk < CAP) buckets[(size_t)r * CAP + rk] = colsIn[i];
        }
    } else {
        // W f32 -> bf16
        int i = (b - nconvx - nscat) * 256 + tid;
        if (i < 256 * 256) Wb[i] = f2bf(W[i]);
    }
}

// ================= K2: gemm_h + fused a1/a2 epilogue ============================
// block = 4 waves, tile 32 nodes x 256 outs; wave w covers outs [w*64,w*64+64).
// a1/a2 computed from f32 accumulators (pre bf16 rounding) + bias.
__global__ __launch_bounds__(256) void k2_gemm(
    const unsigned short* __restrict__ Xb, const unsigned short* __restrict__ Wb,
    const float* __restrict__ bvec, unsigned short* __restrict__ Hb,
    const float* __restrict__ wa1, const float* __restrict__ ba1,
    const float* __restrict__ wa2, const float* __restrict__ ba2,
    float* __restrict__ a1, float* __restrict__ a2) {
    __shared__ float red[2][4][32];   // [a1|a2][wave][node-in-tile]
    const int tid = threadIdx.x;
    const int lane = tid & 63;
    const int wave = tid >> 6;
    const int l15 = lane & 15, quad = lane >> 4;
    const int nbase = blockIdx.x * 32;
    const int obase = wave * 64;

    f32x4 acc[2][4] = {};
#pragma unroll
    for (int k = 0; k < 256; k += 32) {
        s16x8 afr[2];
#pragma unroll
        for (int mt = 0; mt < 2; ++mt)
            afr[mt] = *(const s16x8*)(Xb + (size_t)(nbase + mt * 16 + l15) * 256 + k + quad * 8);
#pragma unroll
        for (int t = 0; t < 4; ++t) {
            s16x8 bfr = *(const s16x8*)(Wb + (size_t)(obase + t * 16 + l15) * 256 + k + quad * 8);
            acc[0][t] = __builtin_amdgcn_mfma_f32_16x16x32_bf16(afr[0], bfr, acc[0][t], 0, 0, 0);
            acc[1][t] = __builtin_amdgcn_mfma_f32_16x16x32_bf16(afr[1], bfr, acc[1][t], 0, 0, 0);
        }
    }
    float bvv[4], w1v[4], w2v[4];
#pragma unroll
    for (int t = 0; t < 4; ++t) {
        int o = obase + t * 16 + l15;
        bvv[t] = bvec[o];
        w1v[t] = wa1[o];
        w2v[t] = wa2[o];
    }
#pragma unroll
    for (int mt = 0; mt < 2; ++mt) {
#pragma unroll
        for (int r = 0; r < 4; ++r) {
            const int node = nbase + mt * 16 + quad * 4 + r;
            float h0 = acc[mt][0][r] + bvv[0];
            float h1 = acc[mt][1][r] + bvv[1];
            float h2 = acc[mt][2][r] + bvv[2];
            float h3 = acc[mt][3][r] + bvv[3];
            unsigned short* hp = Hb + (size_t)node * 256 + obase + l15;
            hp[0]  = f2bf(h0);
            hp[16] = f2bf(h1);
            hp[32] = f2bf(h2);
            hp[48] = f2bf(h3);
            float p1 = h0 * w1v[0] + h1 * w1v[1] + h2 * w1v[2] + h3 * w1v[3];
            float p2 = h0 * w2v[0] + h1 * w2v[1] + h2 * w2v[2] + h3 * w2v[3];
#pragma unroll
            for (int m = 1; m < 16; m <<= 1) {  // reduce over l15 group
                p1 += __shfl_xor(p1, m);
                p2 += __shfl_xor(p2, m);
            }
            if (l15 == 0) {
                red[0][wave][mt * 16 + quad * 4 + r] = p1;
                red[1][wave][mt * 16 + quad * 4 + r] = p2;
            }
        }
    }
    __syncthreads();
    if (tid < 32) {
        a1[nbase + tid] = red[0][0][tid] + red[0][1][tid] + red[0][2][tid] + red[0][3][tid] + ba1[0];
    } else if (tid < 64) {
        int t2 = tid - 32;
        a2[nbase + t2] = red[1][0][t2] + red[1][1][t2] + red[1][2][t2] + red[1][3][t2] + ba2[0];
    }
}

// ================= single-pass streaming aggregation ============================
// Gather-traffic-bound at the L2-miss/fabric wall (~3.85 TB/s): R2-R4 proved all
// structure/VALU/phasing changes around the gather are free, so ev is computed
// inline (a2 is 400 KB, L1/L2-resident) from the contiguous per-node bucket.
// Wave split into halves: half h processes edges i+h; 32 lanes x dwordx4 = one
// full 512 B H row per half. Halves combined at the end via shfl_xor(32).
__device__ inline float evf(float a1n, float av) {
    float v = a1n + av;
    v = (v > 0.0f) ? v : 0.01f * v;
    return __expf(v);
}

__global__ __launch_bounds__(256) void aggregate(
    const int* __restrict__ cnt, const int* __restrict__ buckets,
    const float* __restrict__ a1v, const float* __restrict__ a2v,
    const unsigned short* __restrict__ Hb, float* __restrict__ out) {
    const int lane = threadIdx.x & 63;
    const int wave = threadIdx.x >> 6;
    const int q = lane & 31;
    const int half = lane >> 5;
    const int node = blockIdx.x * 4 + wave;
    int deg = cnt[node];
    if (deg > CAP) deg = CAP;
    const int* __restrict__ pp = buckets + (size_t)node * CAP;
    const unsigned short* __restrict__ hb_q = Hb + q * 8;
    const float a1n = a1v[node];

    float acc[8] = {0, 0, 0, 0, 0, 0, 0, 0};
    float s = 0.0f;

    int i = 0;
    int c0, c1, c2, c3;
    bool have = (8 <= deg);
    if (have) {
        c0 = pp[half]; c1 = pp[2 + half]; c2 = pp[4 + half]; c3 = pp[6 + half];
    }
    while (have) {
        int d0 = c0, d1 = c1, d2 = c2, d3 = c3;
        int ni = i + 8;
        bool nhave = (ni + 8 <= deg);
        if (nhave) {  // prefetch next batch's cols under this batch's row loads
            c0 = pp[ni + half]; c1 = pp[ni + 2 + half];
            c2 = pp[ni + 4 + half]; c3 = pp[ni + 6 + half];
        }
        float av0 = a2v[d0], av1 = a2v[d1], av2 = a2v[d2], av3 = a2v[d3];
        uint4 h0 = *(const uint4*)(hb_q + (size_t)d0 * 256);
        uint4 h1 = *(const uint4*)(hb_q + (size_t)d1 * 256);
        uint4 h2 = *(const uint4*)(hb_q + (size_t)d2 * 256);
        uint4 h3 = *(const uint4*)(hb_q + (size_t)d3 * 256);
        float w0 = evf(a1n, av0), w1 = evf(a1n, av1);
        float w2 = evf(a1n, av2), w3 = evf(a1n, av3);
        s += (w0 + w1) + (w2 + w3);
        acc[0] += w0 * bf_lo(h0.x); acc[1] += w0 * bf_hi(h0.x);
        acc[2] += w0 * bf_lo(h0.y); acc[3] += w0 * bf_hi(h0.y);
        acc[4] += w0 * bf_lo(h0.z); acc[5] += w0 * bf_hi(h0.z);
        acc[6] += w0 * bf_lo(h0.w); acc[7] += w0 * bf_hi(h0.w);
        acc[0] += w1 * bf_lo(h1.x); acc[1] += w1 * bf_hi(h1.x);
        acc[2] += w1 * bf_lo(h1.y); acc[3] += w1 * bf_hi(h1.y);
        acc[4] += w1 * bf_lo(h1.z); acc[5] += w1 * bf_hi(h1.z);
        acc[6] += w1 * bf_lo(h1.w); acc[7] += w1 * bf_hi(h1.w);
        acc[0] += w2 * bf_lo(h2.x); acc[1] += w2 * bf_hi(h2.x);
        acc[2] += w2 * bf_lo(h2.y); acc[3] += w2 * bf_hi(h2.y);
        acc[4] += w2 * bf_lo(h2.z); acc[5] += w2 * bf_hi(h2.z);
        acc[6] += w2 * bf_lo(h2.w); acc[7] += w2 * bf_hi(h2.w);
        acc[0] += w3 * bf_lo(h3.x); acc[1] += w3 * bf_hi(h3.x);
        acc[2] += w3 * bf_lo(h3.y); acc[3] += w3 * bf_hi(h3.y);
        acc[4] += w3 * bf_lo(h3.z); acc[5] += w3 * bf_hi(h3.z);
        acc[6] += w3 * bf_lo(h3.w); acc[7] += w3 * bf_hi(h3.w);
        i = ni;
        have = nhave;
    }
    for (; i < deg; i += 2) {  // tail (< 8 edges)
        int ii = i + half;
        if (ii < deg) {
            int c = pp[ii];
            float w = evf(a1n, a2v[c]);
            uint4 hv = *(const uint4*)(hb_q + (size_t)c * 256);
            s += w;
            acc[0] += w * bf_lo(hv.x); acc[1] += w * bf_hi(hv.x);
            acc[2] += w * bf_lo(hv.y); acc[3] += w * bf_hi(hv.y);
            acc[4] += w * bf_lo(hv.z); acc[5] += w * bf_hi(hv.z);
            acc[6] += w * bf_lo(hv.w); acc[7] += w * bf_hi(hv.w);
        }
    }
#pragma unroll
    for (int j = 0; j < 8; ++j) acc[j] += __shfl_xor(acc[j], 32);
    s += __shfl_xor(s, 32);
    float inv = (s > 0.0f) ? 1.0f / s : 0.0f;
    if (half == 0) {
        float* op = out + (size_t)node * 256 + q * 8;
        f32x4 lo = {acc[0] * inv, acc[1] * inv, acc[2] * inv, acc[3] * inv};
        f32x4 hi = {acc[4] * inv, acc[5] * inv, acc[6] * inv, acc[7] * inv};
        *(f32x4*)op = lo;
        *(f32x4*)(op + 4) = hi;
    }
}

extern "C" void kernel_launch(void* const* d_in, const int* in_sizes, int n_in,
                              void* d_out, int out_size, void* d_ws, size_t ws_size,
                              hipStream_t stream) {
    const float* X   = (const float*)d_in[0];
    const int*   idx = (const int*)d_in[1];
    const float* W   = (const float*)d_in[2];
    const float* b   = (const float*)d_in[3];
    const float* wa1 = (const float*)d_in[4];
    const float* ba1 = (const float*)d_in[5];
    const float* wa2 = (const float*)d_in[6];
    const float* ba2 = (const float*)d_in[7];
    float* out = (float*)d_out;

    const int n = in_sizes[0] / 256;  // 100000
    const int e = in_sizes[1] / 2;    // 3200000

    char* p = (char*)d_ws;
    auto alloc = [&](size_t bytes) -> char* {
        char* r = p;
        p += (bytes + 255) & ~(size_t)255;
        return r;
    };
    unsigned short* Hb = (unsigned short*)alloc((size_t)n * 256 * 2);
    unsigned short* Xb = (unsigned short*)alloc((size_t)n * 256 * 2);
    unsigned short* Wb = (unsigned short*)alloc(256 * 256 * 2);
    float* a1  = (float*)alloc((size_t)n * 4);
    float* a2  = (float*)alloc((size_t)n * 4);
    int* cnt   = (int*)alloc((size_t)n * 4);
    int* buckets = (int*)alloc((size_t)n * CAP * 4);

    const int* rows   = idx;
    const int* colsIn = idx + e;

    hipMemsetAsync(cnt, 0, (size_t)n * 4, stream);

    const int nconvx = n / 8;                   // 12500
    const int nscat  = (e + 255) / 256;         // 12500
    const int nconvw = 256;
    k1_prep<<<nconvx + nscat + nconvw, 256, 0, stream>>>(X, Xb, W, Wb, rows, colsIn,
                                                          cnt, buckets, nconvx, nscat, e);
    k2_gemm<<<n / 32, 256, 0, stream>>>(Xb, Wb, b, Hb, wa1, ba1, wa2, ba2, a1, a2);
    aggregate<<<n / 4, 256, 0, stream>>>(cnt, buckets, a1, a2, Hb, out);
}

// Round 6
// 625.271 us; speedup vs baseline: 1.2179x; 1.2179x over previous
//
#include <hip/hip_runtime.h>
#include <hip/hip_bf16.h>
#include <cstdint>

typedef __attribute__((ext_vector_type(4))) float f32x4;
typedef __attribute__((ext_vector_type(8))) short s16x8;

#define CAP 128   // bucket capacity; deg ~ Poisson(32), P(any node > 128) ~ 1e-13

__device__ inline unsigned short f2bf(float f) {
    unsigned u = __float_as_uint(f);
    u = (u + 0x7fffu + ((u >> 16) & 1u)) >> 16;   // round-to-nearest-even
    return (unsigned short)u;
}
__device__ inline float bf_lo(unsigned x) { return __uint_as_float(x << 16); }
__device__ inline float bf_hi(unsigned x) { return __uint_as_float(x & 0xffff0000u); }

// ================= K1: xcd-scatter | convX | convW (independent, fused) =========
// R5 lesson: 3.2M random 4B bucket writes dirty 3.2M distinct lines -> 205 MB of
// ~8%-useful writebacks at ~0.73 TB/s = the wall. Fix: row-windowed scatter. The
// 8 "adjacent" blocks (blk&7 ~ XCD round-robin heuristic) share one 2048-edge
// chunk; block x keeps only rows in window [x*W,(x+1)*W). All writers of a bucket
// line then live on one XCD -> ~16 same-row writes combine in its L2 before ONE
// full-line writeback (205 MB -> ~15 MB). Cost: 8x rescan of 25.6 MB edge list
// (L3-resident). Correctness is mapping-independent (device-scope atomics);
// wrong XCD guess only degrades combining.
__global__ __launch_bounds__(256) void k1_prep(
    const float* __restrict__ X, unsigned short* __restrict__ Xb,
    const float* __restrict__ W, unsigned short* __restrict__ Wb,
    const int* __restrict__ rows, const int* __restrict__ colsIn,
    int* __restrict__ cnt, int* __restrict__ buckets,
    int nscat8, int nconvx, int e, int n) {
    const int tid = threadIdx.x;
    const int b = blockIdx.x;
    if (b < nscat8) {
        const int myx = b & 7;
        const int chunk = b >> 3;
        const int W8 = (n + 7) >> 3;
        const int lo = myx * W8;
        const int hi = (lo + W8 < n) ? lo + W8 : n;
        const int base = chunk * 2048 + tid;
        int rr[8];
#pragma unroll
        for (int j = 0; j < 8; ++j) {
            int i = base + j * 256;
            rr[j] = (i < e) ? rows[i] : -1;
        }
#pragma unroll
        for (int j = 0; j < 8; ++j) {
            int r = rr[j];
            if (r >= lo && r < hi) {
                int c = colsIn[base + j * 256];
                int rk = atomicAdd(&cnt[r], 1);
                if (rk < CAP) buckets[(size_t)r * CAP + rk] = c;
            }
        }
    } else if (b < nscat8 + nconvx) {
        // X f32 -> bf16, 8 elems/thread (staged; R3 showed direct-f32 gemm slower)
        size_t i = ((size_t)(b - nscat8) * 256 + tid) * 8;
        f32x4 x0 = *(const f32x4*)(X + i);
        f32x4 x1 = *(const f32x4*)(X + i + 4);
        s16x8 r;
        r[0] = (short)f2bf(x0.x); r[1] = (short)f2bf(x0.y);
        r[2] = (short)f2bf(x0.z); r[3] = (short)f2bf(x0.w);
        r[4] = (short)f2bf(x1.x); r[5] = (short)f2bf(x1.y);
        r[6] = (short)f2bf(x1.z); r[7] = (short)f2bf(x1.w);
        *(s16x8*)(Xb + i) = r;
    } else {
        // W f32 -> bf16
        int i = (b - nscat8 - nconvx) * 256 + tid;
        if (i < 256 * 256) Wb[i] = f2bf(W[i]);
    }
}

// ================= K2: gemm_h + fused a1/a2 epilogue, M-tile=64 =================
// block = 4 waves, tile 64 nodes x 256 outs; wave w covers outs [w*64,w*64+64).
// M64 halves B-fragment loads and Wb L2 re-reads per MFMA vs M32 (2.0 vs 1.33
// MFMA/load). Tail block (n=100000 = 64*1562+32) clamps loads, guards stores.
__global__ __launch_bounds__(256) void k2_gemm(
    const unsigned short* __restrict__ Xb, const unsigned short* __restrict__ Wb,
    const float* __restrict__ bvec, unsigned short* __restrict__ Hb,
    const float* __restrict__ wa1, const float* __restrict__ ba1,
    const float* __restrict__ wa2, const float* __restrict__ ba2,
    float* __restrict__ a1, float* __restrict__ a2, int n) {
    __shared__ float red[2][4][64];   // [a1|a2][wave][node-in-tile]
    const int tid = threadIdx.x;
    const int lane = tid & 63;
    const int wave = tid >> 6;
    const int l15 = lane & 15, quad = lane >> 4;
    const int nbase = blockIdx.x * 64;
    const int obase = wave * 64;

    f32x4 acc[4][4] = {};
#pragma unroll
    for (int k = 0; k < 256; k += 32) {
        s16x8 afr[4];
#pragma unroll
        for (int mt = 0; mt < 4; ++mt) {
            int row = nbase + mt * 16 + l15;
            if (row > n - 1) row = n - 1;   // tail clamp (loads only)
            afr[mt] = *(const s16x8*)(Xb + (size_t)row * 256 + k + quad * 8);
        }
#pragma unroll
        for (int t = 0; t < 4; ++t) {
            s16x8 bfr = *(const s16x8*)(Wb + (size_t)(obase + t * 16 + l15) * 256 + k + quad * 8);
#pragma unroll
            for (int mt = 0; mt < 4; ++mt)
                acc[mt][t] = __builtin_amdgcn_mfma_f32_16x16x32_bf16(afr[mt], bfr, acc[mt][t], 0, 0, 0);
        }
    }
    float bvv[4], w1v[4], w2v[4];
#pragma unroll
    for (int t = 0; t < 4; ++t) {
        int o = obase + t * 16 + l15;
        bvv[t] = bvec[o];
        w1v[t] = wa1[o];
        w2v[t] = wa2[o];
    }
#pragma unroll
    for (int mt = 0; mt < 4; ++mt) {
#pragma unroll
        for (int r = 0; r < 4; ++r) {
            const int node = nbase + mt * 16 + quad * 4 + r;
            float h0 = acc[mt][0][r] + bvv[0];
            float h1 = acc[mt][1][r] + bvv[1];
            float h2 = acc[mt][2][r] + bvv[2];
            float h3 = acc[mt][3][r] + bvv[3];
            if (node < n) {
                unsigned short* hp = Hb + (size_t)node * 256 + obase + l15;
                hp[0]  = f2bf(h0);
                hp[16] = f2bf(h1);
                hp[32] = f2bf(h2);
                hp[48] = f2bf(h3);
            }
            float p1 = h0 * w1v[0] + h1 * w1v[1] + h2 * w1v[2] + h3 * w1v[3];
            float p2 = h0 * w2v[0] + h1 * w2v[1] + h2 * w2v[2] + h3 * w2v[3];
#pragma unroll
            for (int m = 1; m < 16; m <<= 1) {  // reduce over l15 group
                p1 += __shfl_xor(p1, m);
                p2 += __shfl_xor(p2, m);
            }
            if (l15 == 0) {
                red[0][wave][mt * 16 + quad * 4 + r] = p1;
                red[1][wave][mt * 16 + quad * 4 + r] = p2;
            }
        }
    }
    __syncthreads();
    if (tid < 64) {
        int node = nbase + tid;
        if (node < n)
            a1[node] = red[0][0][tid] + red[0][1][tid] + red[0][2][tid] + red[0][3][tid] + ba1[0];
    } else if (tid < 128) {
        int t2 = tid - 64;
        int node = nbase + t2;
        if (node < n)
            a2[node] = red[1][0][t2] + red[1][1][t2] + red[1][2][t2] + red[1][3][t2] + ba2[0];
    }
}

// ================= single-pass streaming aggregation ============================
// Gather-traffic-bound at the L2-miss/fabric wall (~3.85 TB/s): R2-R4 proved all
// structure/VALU/phasing changes around the gather are free; ev computed inline
// (a2 is 400 KB, cache-resident). Wave split into halves: half h processes edges
// i+h; 32 lanes x dwordx4 = one full 512 B H row per half.
__device__ inline float evf(float a1n, float av) {
    float v = a1n + av;
    v = (v > 0.0f) ? v : 0.01f * v;
    return __expf(v);
}

__global__ __launch_bounds__(256) void aggregate(
    const int* __restrict__ cnt, const int* __restrict__ buckets,
    const float* __restrict__ a1v, const float* __restrict__ a2v,
    const unsigned short* __restrict__ Hb, float* __restrict__ out) {
    const int lane = threadIdx.x & 63;
    const int wave = threadIdx.x >> 6;
    const int q = lane & 31;
    const int half = lane >> 5;
    const int node = blockIdx.x * 4 + wave;
    int deg = cnt[node];
    if (deg > CAP) deg = CAP;
    const int* __restrict__ pp = buckets + (size_t)node * CAP;
    const unsigned short* __restrict__ hb_q = Hb + q * 8;
    const float a1n = a1v[node];

    float acc[8] = {0, 0, 0, 0, 0, 0, 0, 0};
    float s = 0.0f;

    int i = 0;
    int c0, c1, c2, c3;
    bool have = (8 <= deg);
    if (have) {
        c0 = pp[half]; c1 = pp[2 + half]; c2 = pp[4 + half]; c3 = pp[6 + half];
    }
    while (have) {
        int d0 = c0, d1 = c1, d2 = c2, d3 = c3;
        int ni = i + 8;
        bool nhave = (ni + 8 <= deg);
        if (nhave) {  // prefetch next batch's cols under this batch's row loads
            c0 = pp[ni + half]; c1 = pp[ni + 2 + half];
            c2 = pp[ni + 4 + half]; c3 = pp[ni + 6 + half];
        }
        float av0 = a2v[d0], av1 = a2v[d1], av2 = a2v[d2], av3 = a2v[d3];
        uint4 h0 = *(const uint4*)(hb_q + (size_t)d0 * 256);
        uint4 h1 = *(const uint4*)(hb_q + (size_t)d1 * 256);
        uint4 h2 = *(const uint4*)(hb_q + (size_t)d2 * 256);
        uint4 h3 = *(const uint4*)(hb_q + (size_t)d3 * 256);
        float w0 = evf(a1n, av0), w1 = evf(a1n, av1);
        float w2 = evf(a1n, av2), w3 = evf(a1n, av3);
        s += (w0 + w1) + (w2 + w3);
        acc[0] += w0 * bf_lo(h0.x); acc[1] += w0 * bf_hi(h0.x);
        acc[2] += w0 * bf_lo(h0.y); acc[3] += w0 * bf_hi(h0.y);
        acc[4] += w0 * bf_lo(h0.z); acc[5] += w0 * bf_hi(h0.z);
        acc[6] += w0 * bf_lo(h0.w); acc[7] += w0 * bf_hi(h0.w);
        acc[0] += w1 * bf_lo(h1.x); acc[1] += w1 * bf_hi(h1.x);
        acc[2] += w1 * bf_lo(h1.y); acc[3] += w1 * bf_hi(h1.y);
        acc[4] += w1 * bf_lo(h1.z); acc[5] += w1 * bf_hi(h1.z);
        acc[6] += w1 * bf_lo(h1.w); acc[7] += w1 * bf_hi(h1.w);
        acc[0] += w2 * bf_lo(h2.x); acc[1] += w2 * bf_hi(h2.x);
        acc[2] += w2 * bf_lo(h2.y); acc[3] += w2 * bf_hi(h2.y);
        acc[4] += w2 * bf_lo(h2.z); acc[5] += w2 * bf_hi(h2.z);
        acc[6] += w2 * bf_lo(h2.w); acc[7] += w2 * bf_hi(h2.w);
        acc[0] += w3 * bf_lo(h3.x); acc[1] += w3 * bf_hi(h3.x);
        acc[2] += w3 * bf_lo(h3.y); acc[3] += w3 * bf_hi(h3.y);
        acc[4] += w3 * bf_lo(h3.z); acc[5] += w3 * bf_hi(h3.z);
        acc[6] += w3 * bf_lo(h3.w); acc[7] += w3 * bf_hi(h3.w);
        i = ni;
        have = nhave;
    }
    for (; i < deg; i += 2) {  // tail (< 8 edges)
        int ii = i + half;
        if (ii < deg) {
            int c = pp[ii];
            float w = evf(a1n, a2v[c]);
            uint4 hv = *(const uint4*)(hb_q + (size_t)c * 256);
            s += w;
            acc[0] += w * bf_lo(hv.x); acc[1] += w * bf_hi(hv.x);
            acc[2] += w * bf_lo(hv.y); acc[3] += w * bf_hi(hv.y);
            acc[4] += w * bf_lo(hv.z); acc[5] += w * bf_hi(hv.z);
            acc[6] += w * bf_lo(hv.w); acc[7] += w * bf_hi(hv.w);
        }
    }
#pragma unroll
    for (int j = 0; j < 8; ++j) acc[j] += __shfl_xor(acc[j], 32);
    s += __shfl_xor(s, 32);
    float inv = (s > 0.0f) ? 1.0f / s : 0.0f;
    if (half == 0) {
        float* op = out + (size_t)node * 256 + q * 8;
        f32x4 lo = {acc[0] * inv, acc[1] * inv, acc[2] * inv, acc[3] * inv};
        f32x4 hi = {acc[4] * inv, acc[5] * inv, acc[6] * inv, acc[7] * inv};
        *(f32x4*)op = lo;
        *(f32x4*)(op + 4) = hi;
    }
}

extern "C" void kernel_launch(void* const* d_in, const int* in_sizes, int n_in,
                              void* d_out, int out_size, void* d_ws, size_t ws_size,
                              hipStream_t stream) {
    const float* X   = (const float*)d_in[0];
    const int*   idx = (const int*)d_in[1];
    const float* W   = (const float*)d_in[2];
    const float* b   = (const float*)d_in[3];
    const float* wa1 = (const float*)d_in[4];
    const float* ba1 = (const float*)d_in[5];
    const float* wa2 = (const float*)d_in[6];
    const float* ba2 = (const float*)d_in[7];
    float* out = (float*)d_out;

    const int n = in_sizes[0] / 256;  // 100000
    const int e = in_sizes[1] / 2;    // 3200000

    char* p = (char*)d_ws;
    auto alloc = [&](size_t bytes) -> char* {
        char* r = p;
        p += (bytes + 255) & ~(size_t)255;
        return r;
    };
    unsigned short* Hb = (unsigned short*)alloc((size_t)n * 256 * 2);
    unsigned short* Xb = (unsigned short*)alloc((size_t)n * 256 * 2);
    unsigned short* Wb = (unsigned short*)alloc(256 * 256 * 2);
    float* a1  = (float*)alloc((size_t)n * 4);
    float* a2  = (float*)alloc((size_t)n * 4);
    int* cnt   = (int*)alloc((size_t)n * 4);
    int* buckets = (int*)alloc((size_t)n * CAP * 4);

    const int* rows   = idx;
    const int* colsIn = idx + e;

    hipMemsetAsync(cnt, 0, (size_t)n * 4, stream);

    const int nscat8 = 8 * ((e + 2047) / 2048);   // 12504
    const int nconvx = n / 8;                     // 12500
    const int nconvw = 256;
    k1_prep<<<nscat8 + nconvx + nconvw, 256, 0, stream>>>(X, Xb, W, Wb, rows, colsIn,
                                                           cnt, buckets, nscat8, nconvx, e, n);
    k2_gemm<<<(n + 63) / 64, 256, 0, stream>>>(Xb, Wb, b, Hb, wa1, ba1, wa2, ba2, a1, a2, n);
    aggregate<<<n / 4, 256, 0, stream>>>(cnt, buckets, a1, a2, Hb, out);
}

// Round 7
// 607.705 us; speedup vs baseline: 1.2531x; 1.0289x over previous
//
#include <hip/hip_runtime.h>
#include <hip/hip_bf16.h>
#include <cstdint>

typedef __attribute__((ext_vector_type(4))) float f32x4;
typedef __attribute__((ext_vector_type(8))) short s16x8;

#define CAP 128   // bucket capacity; deg ~ Poisson(32), P(any node > 128) ~ 1e-13

__device__ inline unsigned short f2bf(float f) {
    unsigned u = __float_as_uint(f);
    u = (u + 0x7fffu + ((u >> 16) & 1u)) >> 16;   // round-to-nearest-even
    return (unsigned short)u;
}
__device__ inline float bf_lo(unsigned x) { return __uint_as_float(x << 16); }
__device__ inline float bf_hi(unsigned x) { return __uint_as_float(x & 0xffff0000u); }

// ================= K1: xcd-windowed scatter | convW =============================
// (convX removed -- X is now staged inside k2's LDS, killing the Xb round-trip.)
// R5 lesson: 3.2M random 4B bucket writes dirty 3.2M lines -> 205 MB of ~8%-useful
// writebacks. Fix: 8 row-windowed passes; all writers of a bucket line live on one
// XCD-ish set -> writes combine in L2 before one full-line writeback. Low VGPR (12)
// keeps scatter occupancy high -- deliberately NOT fused with the gemm (whose ~130
// VGPR would halve scatter's wave count).
__global__ __launch_bounds__(256) void k1_prep(
    const float* __restrict__ W, unsigned short* __restrict__ Wb,
    const int* __restrict__ rows, const int* __restrict__ colsIn,
    int* __restrict__ cnt, int* __restrict__ buckets,
    int nscat8, int e, int n) {
    const int tid = threadIdx.x;
    const int b = blockIdx.x;
    if (b < nscat8) {
        const int myx = b & 7;
        const int chunk = b >> 3;
        const int W8 = (n + 7) >> 3;
        const int lo = myx * W8;
        const int hi = (lo + W8 < n) ? lo + W8 : n;
        const int base = chunk * 2048 + tid;
        int rr[8], cc[8];
#pragma unroll
        for (int j = 0; j < 8; ++j) {   // dense upfront loads: deep MLP, no divergence
            int i = base + j * 256;
            rr[j] = (i < e) ? rows[i] : -1;
            cc[j] = (i < e) ? colsIn[i] : 0;
        }
#pragma unroll
        for (int j = 0; j < 8; ++j) {
            int r = rr[j];
            if (r >= lo && r < hi) {
                int rk = atomicAdd(&cnt[r], 1);
                if (rk < CAP) buckets[(size_t)r * CAP + rk] = cc[j];
            }
        }
    } else {
        // W f32 -> bf16
        int i = (b - nscat8) * 256 + tid;
        if (i < 256 * 256) Wb[i] = f2bf(W[i]);
    }
}

// ================= K2: gemm_h, X staged f32->bf16 in LDS, fused a1/a2 ===========
// block = 4 waves, tile 64 nodes x 256 outs; wave w covers outs [w*64,w*64+64).
// X tile (64x256 f32) is loaded coalesced ONCE, converted outside the k-loop
// (fixes R3's in-loop-f2bf regression), stored to LDS with row stride 264 shorts
// (528 B): row-to-row bank shift of 4 spreads same-column fragment reads across
// 8 bank-groups (~2-way = free, m136). A-fragments then come from ds_read_b128
// instead of 16-line strided HBM loads -- removes the Xb round-trip (102 MB) and
// the HBM latency from the inner loop. Tail block clamps loads, guards stores.
__global__ __launch_bounds__(256) void k2_gemm(
    const float* __restrict__ X, const unsigned short* __restrict__ Wb,
    const float* __restrict__ bvec, unsigned short* __restrict__ Hb,
    const float* __restrict__ wa1, const float* __restrict__ ba1,
    const float* __restrict__ wa2, const float* __restrict__ ba2,
    float* __restrict__ a1, float* __restrict__ a2, int n) {
    __shared__ short xs[64 * 264];    // 33.8 KB
    __shared__ float red[2][4][64];   // [a1|a2][wave][node-in-tile]
    const int tid = threadIdx.x;
    const int lane = tid & 63;
    const int wave = tid >> 6;
    const int l15 = lane & 15, quad = lane >> 4;
    const int nbase = blockIdx.x * 64;
    const int obase = wave * 64;

    // ---- stage X tile -> LDS bf16 (coalesced: 32 threads cover one 1 KB row) ----
    {
        const int col = (tid & 31) * 8;
        const int rb = tid >> 5;
#pragma unroll
        for (int c = 0; c < 8; ++c) {
            int row = c * 8 + rb;
            int grow = nbase + row;
            if (grow > n - 1) grow = n - 1;   // tail clamp (stores guarded later)
            const float* xp = X + (size_t)grow * 256 + col;
            f32x4 x0 = *(const f32x4*)xp;
            f32x4 x1 = *(const f32x4*)(xp + 4);
            s16x8 r;
            r[0] = (short)f2bf(x0.x); r[1] = (short)f2bf(x0.y);
            r[2] = (short)f2bf(x0.z); r[3] = (short)f2bf(x0.w);
            r[4] = (short)f2bf(x1.x); r[5] = (short)f2bf(x1.y);
            r[6] = (short)f2bf(x1.z); r[7] = (short)f2bf(x1.w);
            *(s16x8*)(xs + row * 264 + col) = r;
        }
    }
    __syncthreads();

    f32x4 acc[4][4] = {};
#pragma unroll
    for (int k = 0; k < 256; k += 32) {
        s16x8 afr[4];
#pragma unroll
        for (int mt = 0; mt < 4; ++mt)
            afr[mt] = *(const s16x8*)(xs + (mt * 16 + l15) * 264 + k + quad * 8);
#pragma unroll
        for (int t = 0; t < 4; ++t) {
            s16x8 bfr = *(const s16x8*)(Wb + (size_t)(obase + t * 16 + l15) * 256 + k + quad * 8);
#pragma unroll
            for (int mt = 0; mt < 4; ++mt)
                acc[mt][t] = __builtin_amdgcn_mfma_f32_16x16x32_bf16(afr[mt], bfr, acc[mt][t], 0, 0, 0);
        }
    }
    float bvv[4], w1v[4], w2v[4];
#pragma unroll
    for (int t = 0; t < 4; ++t) {
        int o = obase + t * 16 + l15;
        bvv[t] = bvec[o];
        w1v[t] = wa1[o];
        w2v[t] = wa2[o];
    }
#pragma unroll
    for (int mt = 0; mt < 4; ++mt) {
#pragma unroll
        for (int r = 0; r < 4; ++r) {
            const int node = nbase + mt * 16 + quad * 4 + r;
            float h0 = acc[mt][0][r] + bvv[0];
            float h1 = acc[mt][1][r] + bvv[1];
            float h2 = acc[mt][2][r] + bvv[2];
            float h3 = acc[mt][3][r] + bvv[3];
            if (node < n) {
                unsigned short* hp = Hb + (size_t)node * 256 + obase + l15;
                hp[0]  = f2bf(h0);
                hp[16] = f2bf(h1);
                hp[32] = f2bf(h2);
                hp[48] = f2bf(h3);
            }
            float p1 = h0 * w1v[0] + h1 * w1v[1] + h2 * w1v[2] + h3 * w1v[3];
            float p2 = h0 * w2v[0] + h1 * w2v[1] + h2 * w2v[2] + h3 * w2v[3];
#pragma unroll
            for (int m = 1; m < 16; m <<= 1) {  // reduce over l15 group
                p1 += __shfl_xor(p1, m);
                p2 += __shfl_xor(p2, m);
            }
            if (l15 == 0) {
                red[0][wave][mt * 16 + quad * 4 + r] = p1;
                red[1][wave][mt * 16 + quad * 4 + r] = p2;
            }
        }
    }
    __syncthreads();
    if (tid < 64) {
        int node = nbase + tid;
        if (node < n)
            a1[node] = red[0][0][tid] + red[0][1][tid] + red[0][2][tid] + red[0][3][tid] + ba1[0];
    } else if (tid < 128) {
        int t2 = tid - 64;
        int node = nbase + t2;
        if (node < n)
            a2[node] = red[1][0][t2] + red[1][1][t2] + red[1][2][t2] + red[1][3][t2] + ba2[0];
    }
}

// ================= single-pass streaming aggregation (frozen: gather wall) ======
// R2-R4: every structure/VALU/phasing change around the gather was free ->
// bound by L2-miss gather traffic (~3.85 TB/s effective). ev computed inline
// (a2 is 400 KB, cache-resident). Wave split into halves: half h processes edges
// i+h; 32 lanes x dwordx4 = one full 512 B H row per half.
__device__ inline float evf(float a1n, float av) {
    float v = a1n + av;
    v = (v > 0.0f) ? v : 0.01f * v;
    return __expf(v);
}

__global__ __launch_bounds__(256) void aggregate(
    const int* __restrict__ cnt, const int* __restrict__ buckets,
    const float* __restrict__ a1v, const float* __restrict__ a2v,
    const unsigned short* __restrict__ Hb, float* __restrict__ out) {
    const int lane = threadIdx.x & 63;
    const int wave = threadIdx.x >> 6;
    const int q = lane & 31;
    const int half = lane >> 5;
    const int node = blockIdx.x * 4 + wave;
    int deg = cnt[node];
    if (deg > CAP) deg = CAP;
    const int* __restrict__ pp = buckets + (size_t)node * CAP;
    const unsigned short* __restrict__ hb_q = Hb + q * 8;
    const float a1n = a1v[node];

    float acc[8] = {0, 0, 0, 0, 0, 0, 0, 0};
    float s = 0.0f;

    int i = 0;
    int c0, c1, c2, c3;
    bool have = (8 <= deg);
    if (have) {
        c0 = pp[half]; c1 = pp[2 + half]; c2 = pp[4 + half]; c3 = pp[6 + half];
    }
    while (have) {
        int d0 = c0, d1 = c1, d2 = c2, d3 = c3;
        int ni = i + 8;
        bool nhave = (ni + 8 <= deg);
        if (nhave) {  // prefetch next batch's cols under this batch's row loads
            c0 = pp[ni + half]; c1 = pp[ni + 2 + half];
            c2 = pp[ni + 4 + half]; c3 = pp[ni + 6 + half];
        }
        float av0 = a2v[d0], av1 = a2v[d1], av2 = a2v[d2], av3 = a2v[d3];
        uint4 h0 = *(const uint4*)(hb_q + (size_t)d0 * 256);
        uint4 h1 = *(const uint4*)(hb_q + (size_t)d1 * 256);
        uint4 h2 = *(const uint4*)(hb_q + (size_t)d2 * 256);
        uint4 h3 = *(const uint4*)(hb_q + (size_t)d3 * 256);
        float w0 = evf(a1n, av0), w1 = evf(a1n, av1);
        float w2 = evf(a1n, av2), w3 = evf(a1n, av3);
        s += (w0 + w1) + (w2 + w3);
        acc[0] += w0 * bf_lo(h0.x); acc[1] += w0 * bf_hi(h0.x);
        acc[2] += w0 * bf_lo(h0.y); acc[3] += w0 * bf_hi(h0.y);
        acc[4] += w0 * bf_lo(h0.z); acc[5] += w0 * bf_hi(h0.z);
        acc[6] += w0 * bf_lo(h0.w); acc[7] += w0 * bf_hi(h0.w);
        acc[0] += w1 * bf_lo(h1.x); acc[1] += w1 * bf_hi(h1.x);
        acc[2] += w1 * bf_lo(h1.y); acc[3] += w1 * bf_hi(h1.y);
        acc[4] += w1 * bf_lo(h1.z); acc[5] += w1 * bf_hi(h1.z);
        acc[6] += w1 * bf_lo(h1.w); acc[7] += w1 * bf_hi(h1.w);
        acc[0] += w2 * bf_lo(h2.x); acc[1] += w2 * bf_hi(h2.x);
        acc[2] += w2 * bf_lo(h2.y); acc[3] += w2 * bf_hi(h2.y);
        acc[4] += w2 * bf_lo(h2.z); acc[5] += w2 * bf_hi(h2.z);
        acc[6] += w2 * bf_lo(h2.w); acc[7] += w2 * bf_hi(h2.w);
        acc[0] += w3 * bf_lo(h3.x); acc[1] += w3 * bf_hi(h3.x);
        acc[2] += w3 * bf_lo(h3.y); acc[3] += w3 * bf_hi(h3.y);
        acc[4] += w3 * bf_lo(h3.z); acc[5] += w3 * bf_hi(h3.z);
        acc[6] += w3 * bf_lo(h3.w); acc[7] += w3 * bf_hi(h3.w);
        i = ni;
        have = nhave;
    }
    for (; i < deg; i += 2) {  // tail (< 8 edges)
        int ii = i + half;
        if (ii < deg) {
            int c = pp[ii];
            float w = evf(a1n, a2v[c]);
            uint4 hv = *(const uint4*)(hb_q + (size_t)c * 256);
            s += w;
            acc[0] += w * bf_lo(hv.x); acc[1] += w * bf_hi(hv.x);
            acc[2] += w * bf_lo(hv.y); acc[3] += w * bf_hi(hv.y);
            acc[4] += w * bf_lo(hv.z); acc[5] += w * bf_hi(hv.z);
            acc[6] += w * bf_lo(hv.w); acc[7] += w * bf_hi(hv.w);
        }
    }
#pragma unroll
    for (int j = 0; j < 8; ++j) acc[j] += __shfl_xor(acc[j], 32);
    s += __shfl_xor(s, 32);
    float inv = (s > 0.0f) ? 1.0f / s : 0.0f;
    if (half == 0) {
        float* op = out + (size_t)node * 256 + q * 8;
        f32x4 lo = {acc[0] * inv, acc[1] * inv, acc[2] * inv, acc[3] * inv};
        f32x4 hi = {acc[4] * inv, acc[5] * inv, acc[6] * inv, acc[7] * inv};
        *(f32x4*)op = lo;
        *(f32x4*)(op + 4) = hi;
    }
}

extern "C" void kernel_launch(void* const* d_in, const int* in_sizes, int n_in,
                              void* d_out, int out_size, void* d_ws, size_t ws_size,
                              hipStream_t stream) {
    const float* X   = (const float*)d_in[0];
    const int*   idx = (const int*)d_in[1];
    const float* W   = (const float*)d_in[2];
    const float* b   = (const float*)d_in[3];
    const float* wa1 = (const float*)d_in[4];
    const float* ba1 = (const float*)d_in[5];
    const float* wa2 = (const float*)d_in[6];
    const float* ba2 = (const float*)d_in[7];
    float* out = (float*)d_out;

    const int n = in_sizes[0] / 256;  // 100000
    const int e = in_sizes[1] / 2;    // 3200000

    char* p = (char*)d_ws;
    auto alloc = [&](size_t bytes) -> char* {
        char* r = p;
        p += (bytes + 255) & ~(size_t)255;
        return r;
    };
    unsigned short* Hb = (unsigned short*)alloc((size_t)n * 256 * 2);
    unsigned short* Wb = (unsigned short*)alloc(256 * 256 * 2);
    float* a1  = (float*)alloc((size_t)n * 4);
    float* a2  = (float*)alloc((size_t)n * 4);
    int* cnt   = (int*)alloc((size_t)n * 4);
    int* buckets = (int*)alloc((size_t)n * CAP * 4);

    const int* rows   = idx;
    const int* colsIn = idx + e;

    hipMemsetAsync(cnt, 0, (size_t)n * 4, stream);

    const int nscat8 = 8 * ((e + 2047) / 2048);   // 12504
    const int nconvw = 256;
    k1_prep<<<nscat8 + nconvw, 256, 0, stream>>>(W, Wb, rows, colsIn,
                                                  cnt, buckets, nscat8, e, n);
    k2_gemm<<<(n + 63) / 64, 256, 0, stream>>>(X, Wb, b, Hb, wa1, ba1, wa2, ba2, a1, a2, n);
    aggregate<<<n / 4, 256, 0, stream>>>(cnt, buckets, a1, a2, Hb, out);
}